// Round 13
// baseline (644.020 us; speedup 1.0000x reference)
//
#include <hip/hip_runtime.h>

#define IN_F 4096
#define OUT_F 16384
#define MTOK 8192   // B*S

#define BM 256
#define BN 256
#define BK 64
#define NKT (IN_F / BK)   // 64 K-tiles

typedef __attribute__((ext_vector_type(4)))  int   i32x4;
typedef __attribute__((ext_vector_type(4)))  float f32x4;

__device__ __forceinline__ void gload_lds16(const void* g, void* l) {
    __builtin_amdgcn_global_load_lds(
        (const __attribute__((address_space(1))) void*)g,
        (__attribute__((address_space(3))) void*)l,
        16, 0, 0);
}

// ---------------------------------------------------------------------------
// Kernel 1 (fused prepass): blocks [0,MTOK) = per-token absmax + int8 quant;
// blocks [MTOK, MTOK+8192) = ternary int32 -> int8 pack (grid-stride).
// ---------------------------------------------------------------------------
__global__ __launch_bounds__(256) void k_pre(const float* __restrict__ x,
                                             const int*   __restrict__ wt,
                                             char*  __restrict__ xq,
                                             float* __restrict__ xs,
                                             int*   __restrict__ w8) {
    const int t = threadIdx.x;
    if (blockIdx.x < MTOK) {
        const int m = blockIdx.x;
        const float* xrow = x + (size_t)m * IN_F;

        f32x4 v[4];
        float mx = 0.f;
#pragma unroll
        for (int i = 0; i < 4; ++i) {
            v[i] = *(const f32x4*)&xrow[(i * 256 + t) * 4];
            mx = fmaxf(mx, fmaxf(fmaxf(fabsf(v[i].x), fabsf(v[i].y)),
                                 fmaxf(fabsf(v[i].z), fabsf(v[i].w))));
        }
#pragma unroll
        for (int off = 32; off > 0; off >>= 1)
            mx = fmaxf(mx, __shfl_xor(mx, off));

        __shared__ float wmax[4];
        const int wid = t >> 6;
        if ((t & 63) == 0) wmax[wid] = mx;
        __syncthreads();
        const float scale = fmaxf(fmaxf(fmaxf(wmax[0], wmax[1]),
                                        fmaxf(wmax[2], wmax[3])), 1e-5f);
        const float inv = 127.0f / scale;

        int* xqi = (int*)(xq + (size_t)m * IN_F);
#pragma unroll
        for (int i = 0; i < 4; ++i) {
            int q0 = (int)rintf(fminf(fmaxf(v[i].x * inv, -128.f), 127.f));
            int q1 = (int)rintf(fminf(fmaxf(v[i].y * inv, -128.f), 127.f));
            int q2 = (int)rintf(fminf(fmaxf(v[i].z * inv, -128.f), 127.f));
            int q3 = (int)rintf(fminf(fmaxf(v[i].w * inv, -128.f), 127.f));
            xqi[i * 256 + t] = (q0 & 255) | ((q1 & 255) << 8) |
                               ((q2 & 255) << 16) | (q3 << 24);
        }
        if (t == 0) xs[m] = scale;
    } else {
        const int total4 = OUT_F * IN_F / 4;
        int idx = (blockIdx.x - MTOK) * 256 + t;
        const int stride = 8192 * 256;
        for (; idx < total4; idx += stride) {
            i32x4 w = *(const i32x4*)&wt[(size_t)idx * 4];
            w8[idx] = (w.x & 255) | ((w.y & 255) << 8) |
                      ((w.z & 255) << 16) | (w.w << 24);
        }
    }
}

// ---------------------------------------------------------------------------
// Kernel 2: i8 GEMM — 256x256 tile, BK=64, 8 waves (2Mx4N, wave 128x64),
// 3-buffer LDS rotation + spread-phase reads + ONE barrier per K-tile.
//
// Combination of measured-proven parts:
//  - R10's 3-buffer rotation + vmcnt FIFO ledger (1 BAR + 1 VM per K-tile):
//    body(kt) reads buf kt%3, stages kt+2 into (kt+2)%3 = (kt-1)%3 whose
//    reads all retired before body(kt-1)'s ending barrier (every ds_read is
//    consumed by an in-body MFMA, so its lgkm wait precedes the BAR).
//  - R10's 64B-row swizzle (0 conflicts measured): phys chunk =
//    logical ^ ((row>>1)&3); staging permutes the global SOURCE within each
//    row's 64B only; frag read row=lane&15, chunk=(lane>>4)^((lane>>1)&3).
//  - R12's spread reads: frags are loaded in 3 groups interleaved with the
//    4 MFMA quadrant clusters, so the LDS queue drains under MFMAs (counted
//    lgkmcnt by compiler; no inline lgkm asm -> rule #18 safe).
// Ledger: prologue {s0:4,s1:4} VM4 retires s0. Body kt issues s(kt+2);
// at VM point outstanding = {s(kt+1):4, s(kt+2):4} -> VM4 retires exactly
// s(kt+1) (read next body). Tail (kt>=62): VM0.
// ---------------------------------------------------------------------------
__global__ __launch_bounds__(512, 2) void k_gemm(
    const char*  __restrict__ Aq,     // [MTOK][IN_F] int8
    const char*  __restrict__ Bq,     // [OUT_F][IN_F] int8
    const float* __restrict__ xs,     // [MTOK]
    const float* __restrict__ wsp,    // [1]
    float*       __restrict__ C) {    // [MTOK][OUT_F]
    __shared__ __align__(16) char lds[98304];   // A: 0..48K, B: 48K..96K

    const int t    = threadIdx.x;
    const int lane = t & 63;
    const int wid  = t >> 6;
    const int wr   = wid >> 2;        // 0..1  (M half, 128 rows)
    const int wc   = wid & 3;         // 0..3  (N quarter, 64 cols)

    // XCD band mapping: grid 2048 = 32(M) x 64(N); XCD (bid&7) owns an
    // 8-wide bn band. Bijective.
    const int bid = blockIdx.x;
    const int bn  = (bid & 7) * 8 + ((bid >> 3) & 7);
    const int bm  = bid >> 6;
    const int mBase = bm * BM;
    const int nBase = bn * BN;

    // --- staging source (R10-proven): thread t -> row t>>2, phys chunk t&3,
    // logical source chunk (t&3)^((t>>3)&3). Second load: row+128 (same c0,
    // (row>>1)&3 unchanged since 128 % 8 == 0).
    const int r0 = t >> 2;
    const int c0 = (((t & 3) ^ ((t >> 3) & 3)) << 4);

#define STAGE(kt, bx) do {                                                     \
        const size_t ks = (size_t)(kt) * BK;                                   \
        gload_lds16(Aq + (size_t)(mBase + r0) * IN_F + ks + c0,                \
                    lds + (bx) * 16384 + wid * 1024);                          \
        gload_lds16(Aq + (size_t)(mBase + 128 + r0) * IN_F + ks + c0,          \
                    lds + (bx) * 16384 + 8192 + wid * 1024);                   \
        gload_lds16(Bq + (size_t)(nBase + r0) * IN_F + ks + c0,                \
                    lds + 49152 + (bx) * 16384 + wid * 1024);                  \
        gload_lds16(Bq + (size_t)(nBase + 128 + r0) * IN_F + ks + c0,          \
                    lds + 49152 + (bx) * 16384 + 8192 + wid * 1024);           \
    } while (0)

    // --- fragment read (R10-proven, 0 conflicts): row = lane&15,
    // phys chunk = (lane>>4) ^ ((row>>1)&3)
    const int fOff = (lane & 15) * 64 + ((((lane >> 4) ^ (lane >> 1)) & 3) << 4);
    const char* ldsA = lds + wr * 8192;            // + x*16384 + mi*1024
    const char* ldsB = lds + 49152 + wc * 4096;    // + x*16384 + ni*1024

#define MFMA8(Af, AB, Bf, BB, NIB)                                             \
    __builtin_amdgcn_s_setprio(1);                                             \
    _Pragma("unroll")                                                          \
    for (int mi = 0; mi < 4; ++mi)                                             \
        _Pragma("unroll")                                                      \
        for (int ni = 0; ni < 2; ++ni)                                         \
            acc[(AB) + mi][(NIB) + ni] =                                       \
                __builtin_amdgcn_mfma_i32_16x16x64_i8(                         \
                    Af[mi], Bf[ni], acc[(AB) + mi][(NIB) + ni], 0, 0, 0);      \
    __builtin_amdgcn_s_setprio(0);

#define BAR()   __builtin_amdgcn_s_barrier()
#define VM4()   asm volatile("s_waitcnt vmcnt(4)" ::: "memory")
#define VM0()   asm volatile("s_waitcnt vmcnt(0)" ::: "memory")

    i32x4 acc[8][4];
#pragma unroll
    for (int i = 0; i < 8; ++i)
#pragma unroll
        for (int j = 0; j < 4; ++j)
            acc[i][j] = (i32x4){0, 0, 0, 0};

    // ---- prologue: tile0 -> buf0, tile1 -> buf1; VM4 retires tile0 exactly
    STAGE(0, 0);
    STAGE(1, 1);
    VM4();
    BAR();

    int x = 0, x2 = 2;   // kt % 3, (kt+2) % 3
    for (int kt = 0; kt < NKT; ++kt) {
        const int xo = x * 16384;
        const bool more = (kt + 2 < NKT);
        i32x4 aLo[4], aHi[4], bLo[2], bHi[2];

        // ---- sub1: frags for (lo,lo); MFMA cluster
#pragma unroll
        for (int mi = 0; mi < 4; ++mi)
            aLo[mi] = *(const i32x4*)(ldsA + xo + mi * 1024 + fOff);
#pragma unroll
        for (int ni = 0; ni < 2; ++ni)
            bLo[ni] = *(const i32x4*)(ldsB + xo + ni * 1024 + fOff);
        MFMA8(aLo, 0, bLo, 0, 0);

        // ---- sub2: bHi; MFMA (lo,hi)   (issues while sub1 MFMAs run)
#pragma unroll
        for (int ni = 0; ni < 2; ++ni)
            bHi[ni] = *(const i32x4*)(ldsB + xo + (2 + ni) * 1024 + fOff);
        MFMA8(aLo, 0, bHi, 0, 2);

        // ---- sub3: aHi + stage(kt+2); MFMA (hi,hi)
#pragma unroll
        for (int mi = 0; mi < 4; ++mi)
            aHi[mi] = *(const i32x4*)(ldsA + xo + (4 + mi) * 1024 + fOff);
        if (more) STAGE(kt + 2, x2);
        MFMA8(aHi, 4, bHi, 0, 2);

        // ---- sub4: MFMA (hi,lo); counted drain; ONE barrier per K-tile
        MFMA8(aHi, 4, bLo, 0, 0);
        if (more) { VM4(); } else { VM0(); }
        BAR();

        x  = (x  == 2) ? 0 : x  + 1;
        x2 = (x2 == 2) ? 0 : x2 + 1;
    }

    // ---- epilogue: D row = (lane>>4)*4 + r, col = lane&15 (verified R1-R12)
    const float wsc = wsp[0] * (1.0f / 127.0f);
#pragma unroll
    for (int mi = 0; mi < 8; ++mi) {
        float rs[4];
#pragma unroll
        for (int r = 0; r < 4; ++r)
            rs[r] = xs[mBase + wr * 128 + mi * 16 + (lane >> 4) * 4 + r] * wsc;
#pragma unroll
        for (int ni = 0; ni < 4; ++ni) {
            const int col = nBase + wc * 64 + ni * 16 + (lane & 15);
#pragma unroll
            for (int r = 0; r < 4; ++r) {
                const int row = mBase + wr * 128 + mi * 16 + (lane >> 4) * 4 + r;
                C[(size_t)row * OUT_F + col] = (float)acc[mi][ni][r] * rs[r];
            }
        }
    }
}

// ---------------------------------------------------------------------------
extern "C" void kernel_launch(void* const* d_in, const int* in_sizes, int n_in,
                              void* d_out, int out_size, void* d_ws, size_t ws_size,
                              hipStream_t stream) {
    const float* x   = (const float*)d_in[0];
    const int*   wt  = (const int*)d_in[1];
    const float* wsp = (const float*)d_in[2];
    float* out = (float*)d_out;

    char*  w8 = (char*)d_ws;
    char*  xq = (char*)d_ws + (size_t)OUT_F * IN_F;
    float* xs = (float*)((char*)d_ws + (size_t)OUT_F * IN_F
                                     + (size_t)MTOK * IN_F);

    k_pre<<<MTOK + 8192, 256, 0, stream>>>(x, wt, xq, xs, (int*)w8);

    const int grid = (MTOK / BM) * (OUT_F / BN);  // 32 * 64 = 2048
    k_gemm<<<grid, 512, 0, stream>>>(xq, w8, xs, wsp, out);
}